// Round 12
// baseline (56.608 us; speedup 1.0000x reference)
//
#include <hip/hip_runtime.h>

#define CIN   64
#define HW    128
#define COUT  128
#define TH    4
#define TW    64
#define PXR   66            // padded pixels per row
#define NITER (TH + 2)      // 6 iterations, two-barrier structure
#define NTHR  1024
#define HSTR  144           // bytes per histogram row (16B aligned)
#define AKSTR 136           // u16 per AK row -> 272 B (16B aligned)
#define SLOT  (PXR * HSTR)  // 9504 B per H ring slot

// LDS layout (bytes), manually packed so overflow reads are well-defined:
//   [0, 38016)        Hm[4] ring slots, 66 rows x 144 B
//   [38016, 59776)    Kt i8[128][128] (prologue) / AK u16[80][136] (loop)
//   [59776, 60928)    Sx int[4][72] reduced (pc<<20)|ps per pixel
//   [60928, 67264)    Sxp int[2][66][12] quad-partials
#define HM_OFF    0
#define KT_OFF    38016
#define SX_OFF    59776
#define SXP_OFF   60928
#define LDS_BYTES 67264

typedef int v4i __attribute__((ext_vector_type(4)));

// lgkm-only barrier: drains LDS ops, leaves global loads/stores in flight.
__device__ __forceinline__ void wg_barrier() {
  asm volatile("s_waitcnt lgkmcnt(0)\n\ts_barrier" ::: "memory");
}

// sum over each aligned 4-lane quad via DPP (VALU pipe, no LDS traffic).
__device__ __forceinline__ int quad_sum(int v) {
  v += __builtin_amdgcn_mov_dpp(v, 0xB1, 0xF, 0xF, true);
  v += __builtin_amdgcn_mov_dpp(v, 0x4E, 0xF, 0xF, true);
  return v;
}

// ---------------------------------------------------------------------------
// Kernel 1: W_tab[o] = sum of quantized weights; Kt_g[o][v] i8 = K[v][o]-128
// where K[v][o] = #{w in o : qw*(128+v) > 32767}, v=0..127 (K<=255, ~7 sigma).
// ---------------------------------------------------------------------------
__global__ __launch_bounds__(512)
void build_tables(const float* __restrict__ weight, int* __restrict__ W_tab,
                  char* __restrict__ Kt_g) {
  __shared__ int qw_s[576];
  __shared__ int red_s[144];
  const int o = blockIdx.x;
  const int t = threadIdx.x;
  for (int j = t; j < 576; j += 512) {
    float w = weight[o * 576 + j];
    int q = (int)rintf(w * 255.f);
    qw_s[j] = q < 0 ? 0 : (q > 255 ? 255 : q);
  }
  __syncthreads();
  const int v = t >> 2, part = t & 3;
  const int i = 128 + v;                     // v==0 -> cnt=0 (qw*128<=32640)
  int cnt = 0;
  const int j0 = part * 144;
  for (int j = j0; j < j0 + 144; ++j) cnt += (qw_s[j] * i) > 32767 ? 1 : 0;
  cnt = quad_sum(cnt);
  if (part == 0) Kt_g[o * 128 + v] = (char)(cnt - 128);
  if (t < 144)
    red_s[t] = qw_s[t * 4] + qw_s[t * 4 + 1] + qw_s[t * 4 + 2] + qw_s[t * 4 + 3];
  __syncthreads();
  if (t == 0) {
    int s = 0;
    for (int kk = 0; kk < 144; ++kk) s += red_s[kk];
    W_tab[o] = s;
  }
}

// ---------------------------------------------------------------------------
// Kernel 2: prefetched quantize -> histogram (LDS atomics) -> i8 MFMA
// (K = 3 stacked rows x 128 bins) -> horizontal 3-sum + emit.
// grid = 512 blocks 1D, XCD-remapped (b = bid&7; per XCD 32 h-strips x 2
// w-tiles, colocated). 1024 threads (16 waves), 67.3 KB LDS -> 2 blocks/CU
// = 32 waves (max). KEY CHANGE vs R11: TW=64 -> each wave's output store is
// 256 B contiguous per (o,h) plane-row (vs 128 B) -> better HBM write
// row-buffer locality (theory: write-granularity-limited at 1.6 TB/s).
// Wave roles in phase 2: 0-9 MFMA (Mt=w>>1 in 0..4, Nh=w&1), 10 Sx-tree,
// 11-15 zero next H slot.
// ---------------------------------------------------------------------------
__global__ __launch_bounds__(NTHR, 4)
void pcilt_main(const float* __restrict__ x, const float* __restrict__ bias,
                const int* __restrict__ W_tab, const char* __restrict__ Kt_g,
                float* __restrict__ out) {
  __shared__ uint4 ldsv[LDS_BYTES / 16];
  char* ldsb = (char*)ldsv;
  unsigned char* HmB  = (unsigned char*)(ldsb + HM_OFF);
  unsigned char* KtB  = (unsigned char*)(ldsb + KT_OFF);
  unsigned short* AK  = (unsigned short*)(ldsb + KT_OFF);
  int* Sx             = (int*)(ldsb + SX_OFF);     // [4][72], 0..65 used
  int* Sxp            = (int*)(ldsb + SXP_OFF);    // [2][66][12]

  const int t   = (int)threadIdx.x;
  const int bid = (int)blockIdx.x;
  const int b  = bid & 7;                          // XCD owns one batch
  const int k  = bid >> 3;                         // 0..63
  const int h0 = (k >> 1) * TH;                    // 32 h-strips
  const int w0 = (k & 1) * TW;                     // 2 w-tiles

  for (int i = t; i < 4096; i += NTHR)
    ((unsigned int*)KtB)[i] = ((const unsigned int*)Kt_g)[i];
  {
    const uint4 z4 = make_uint4(0, 0, 0, 0);
    for (int i = t; i < 4 * SLOT / 16; i += NTHR) ((uint4*)HmB)[i] = z4;
  }

  const int l    = t & 15;
  const int slot = t >> 4;                         // 0..63 pixel slot
  const int w    = t >> 6;                         // wave id 0..15
  const int kq   = (t >> 4) & 3;
  const int we   = t & 63;                         // emit out col
  const int og   = w;                              // emit o-group (8 o each)

  float wf[8], bi[8];
#pragma unroll
  for (int m = 0; m < 8; ++m) {
    wf[m] = (float)W_tab[og * 8 + m];
    bi[m] = bias[og * 8 + m];
  }

  wg_barrier();

  // hoist B-fragments (Kt LDS is dead afterwards; AK reuses its space)
  v4i bfr[4][2];
  const int Mt = w >> 1, Nh = w & 1;
  if (w < 10) {
#pragma unroll
    for (int nt = 0; nt < 4; ++nt)
#pragma unroll
      for (int k64 = 0; k64 < 2; ++k64)
        bfr[nt][k64] = *(const v4i*)(KtB + (Nh * 64 + nt * 16 + l) * 128 +
                                     k64 * 64 + kq * 16);
  }

  float pf0[4], pf1[4];
  const float* xb = x + ((size_t)b * CIN + l * 4) * (HW * HW);
  const size_t cs = (size_t)HW * HW;

#define ISSUE(rn)                                                              \
  {                                                                            \
    const int iy  = h0 + (rn)-1;                                               \
    const int iyc = iy < 0 ? 0 : (iy > 127 ? 127 : iy);                        \
    const bool rok = (iy >= 0) && (iy < HW);                                   \
    int ix = w0 + slot - 1;                                                    \
    int ixc = ix < 0 ? 0 : (ix > 127 ? 127 : ix);                              \
    bool ok = rok && (ix >= 0) && (ix < HW);                                   \
    const float* xp = xb + (size_t)iyc * HW + ixc;                             \
    float v0 = xp[0], v1 = xp[cs], v2 = xp[2 * cs], v3 = xp[3 * cs];           \
    pf0[0] = ok ? v0 : 0.f; pf0[1] = ok ? v1 : 0.f;                            \
    pf0[2] = ok ? v2 : 0.f; pf0[3] = ok ? v3 : 0.f;                            \
    if (slot < 2) {                                                            \
      ix = w0 + TW + slot - 1;                                                 \
      ixc = ix > 127 ? 127 : ix;                                               \
      ok = rok && (ix < HW);                                                   \
      const float* xq = xb + (size_t)iyc * HW + ixc;                           \
      float u0 = xq[0], u1 = xq[cs], u2 = xq[2 * cs], u3 = xq[3 * cs];         \
      pf1[0] = ok ? u0 : 0.f; pf1[1] = ok ? u1 : 0.f;                          \
      pf1[2] = ok ? u2 : 0.f; pf1[3] = ok ? u3 : 0.f;                          \
    }                                                                          \
  }

// Sx: quad_sum (VALU) -> 4 partials/pixel, scatter-written conflict-free.
#define STAGEPX(pf, px)                                                        \
  {                                                                            \
    int q, iv0, iv1, iv2, iv3;                                                 \
    q = (int)rintf((pf)[0] * 255.f); iv0 = q < 0 ? 0 : (q > 255 ? 255 : q);    \
    q = (int)rintf((pf)[1] * 255.f); iv1 = q < 0 ? 0 : (q > 255 ? 255 : q);    \
    q = (int)rintf((pf)[2] * 255.f); iv2 = q < 0 ? 0 : (q > 255 ? 255 : q);    \
    q = (int)rintf((pf)[3] * 255.f); iv3 = q < 0 ? 0 : (q > 255 ? 255 : q);    \
    int pk = (((iv0 > 128) + (iv1 > 128) + (iv2 > 128) + (iv3 > 128)) << 20) + \
             (iv0 + iv1 + iv2 + iv3);                                          \
    pk = quad_sum(pk);                                                         \
    if ((l & 3) == 0) Sxp[sxpb + (px)*12 + (l >> 2)] = pk;                     \
    unsigned char* hp = Hc + (px)*HSTR;                                        \
    if (iv0 > 128) { int v = iv0 - 128; atomicAdd((unsigned int*)(hp + ((v >> 2) << 2)), 1u << ((v & 3) * 8)); } \
    if (iv1 > 128) { int v = iv1 - 128; atomicAdd((unsigned int*)(hp + ((v >> 2) << 2)), 1u << ((v & 3) * 8)); } \
    if (iv2 > 128) { int v = iv2 - 128; atomicAdd((unsigned int*)(hp + ((v >> 2) << 2)), 1u << ((v & 3) * 8)); } \
    if (iv3 > 128) { int v = iv3 - 128; atomicAdd((unsigned int*)(hp + ((v >> 2) << 2)), 1u << ((v & 3) * 8)); } \
  }

  ISSUE(0);

  for (int r = 0; r < NITER; ++r) {
    // ---------------- stage row r from prefetched regs; issue row r+1 ------
    {
      unsigned char* Hc = HmB + (r & 3) * SLOT;
      const int sxpb = (r & 1) * (PXR * 12);
      STAGEPX(pf0, slot);
      if (slot < 2) STAGEPX(pf1, TW + slot);
      if (r + 1 < NITER) ISSUE(r + 1);
    }
    wg_barrier();

    // ---------------- phase 2: MFMA (0-9) / Sx-tree (10) / zero (11-15) ----
    if (r >= 2 && w < 10) {
      v4i acc[4];
#pragma unroll
      for (int nt = 0; nt < 4; ++nt) acc[nt] = (v4i){0, 0, 0, 0};
      const int prow = Mt * 16 + l;              // Mt=4 rows 66..79: garbage
#pragma unroll                                   // reads into AK region,
      for (int st = 0; st < 3; ++st) {           // never emitted
        const unsigned char* Hs = HmB + ((r - 2 + st) & 3) * SLOT +
                                  prow * HSTR + kq * 16;
#pragma unroll
        for (int k64 = 0; k64 < 2; ++k64) {
          const v4i a = *(const v4i*)(Hs + k64 * 64);
#pragma unroll
          for (int nt = 0; nt < 4; ++nt)
            acc[nt] = __builtin_amdgcn_mfma_i32_16x16x64_i8(a, bfr[nt][k64], acc[nt], 0, 0, 0);
        }
      }
      const int pbase = Mt * 16 + kq * 4;
#pragma unroll
      for (int nt = 0; nt < 4; ++nt) {
        const int o = Nh * 64 + nt * 16 + l;
#pragma unroll
        for (int rg = 0; rg < 4; ++rg)
          AK[(pbase + rg) * AKSTR + o] = (unsigned short)acc[nt][rg];
      }
    }
    if (w == 10) {                               // finish Sx: 4 segs -> 1
      const int L = t - 640;                     // 0..63
      const int sb = (r & 1) * (PXR * 12);
      {
        const v4i sq = *(const v4i*)&Sxp[sb + L * 12];
        Sx[(r & 3) * 72 + L] = sq.x + sq.y + sq.z + sq.w;
      }
      if (L < 2) {
        const v4i sq = *(const v4i*)&Sxp[sb + (TW + L) * 12];
        Sx[(r & 3) * 72 + TW + L] = sq.x + sq.y + sq.z + sq.w;
      }
    }
    if (w >= 11) {                               // zero H slot r+1
      uint4* Hn = (uint4*)(HmB + ((r + 1) & 3) * SLOT);
      const uint4 z4 = make_uint4(0, 0, 0, 0);
      for (int i2 = t - 704; i2 < SLOT / 16; i2 += 320) Hn[i2] = z4;
    }
    wg_barrier();

    // ---------------- emit out-row h0 + r - 2 (256 B contiguous/wave) ------
    if (r >= 2) {
      const int h = h0 + r - 2;
      int v9 = 0;
#pragma unroll
      for (int q = 0; q < 3; ++q) {
        const int sl = (r - 2 + q) & 3;
        v9 += Sx[sl * 72 + we] + Sx[sl * 72 + we + 1] + Sx[sl * 72 + we + 2];
      }
      const int sx9 = v9 & 0xFFFFF;
      const int sh9 = v9 >> 20;
      int k0 = 0, k1 = 0, k2 = 0, k3 = 0, k4 = 0, k5 = 0, k6 = 0, k7 = 0;
#pragma unroll
      for (int dx = 0; dx < 3; ++dx) {
        const uint4 p = *(const uint4*)&AK[(we + dx) * AKSTR + og * 8];
        k0 += (int)(short)(p.x & 0xffffu); k1 += (int)(short)(p.x >> 16);
        k2 += (int)(short)(p.y & 0xffffu); k3 += (int)(short)(p.y >> 16);
        k4 += (int)(short)(p.z & 0xffffu); k5 += (int)(short)(p.z >> 16);
        k6 += (int)(short)(p.w & 0xffffu); k7 += (int)(short)(p.w >> 16);
      }
      const int kc = 128 * sh9;
      const float sxf = (float)sx9;
      float* op = out + (((size_t)b * COUT + og * 8) * HW + h) * HW + (w0 + we);
      const size_t os = (size_t)HW * HW;
      op[0 * os] = sxf * wf[0] - 65536.f * (float)(k0 + kc) + bi[0];
      op[1 * os] = sxf * wf[1] - 65536.f * (float)(k1 + kc) + bi[1];
      op[2 * os] = sxf * wf[2] - 65536.f * (float)(k2 + kc) + bi[2];
      op[3 * os] = sxf * wf[3] - 65536.f * (float)(k3 + kc) + bi[3];
      op[4 * os] = sxf * wf[4] - 65536.f * (float)(k4 + kc) + bi[4];
      op[5 * os] = sxf * wf[5] - 65536.f * (float)(k5 + kc) + bi[5];
      op[6 * os] = sxf * wf[6] - 65536.f * (float)(k6 + kc) + bi[6];
      op[7 * os] = sxf * wf[7] - 65536.f * (float)(k7 + kc) + bi[7];
    }
  }
}

// ---------------------------------------------------------------------------
extern "C" void kernel_launch(void* const* d_in, const int* in_sizes, int n_in,
                              void* d_out, int out_size, void* d_ws, size_t ws_size,
                              hipStream_t stream) {
  const float* x      = (const float*)d_in[0];
  const float* weight = (const float*)d_in[1];
  const float* bias   = (const float*)d_in[2];
  float* out = (float*)d_out;

  int*  W_tab = (int*)d_ws;
  char* Kt_g  = (char*)d_ws + 512;

  build_tables<<<128, 512, 0, stream>>>(weight, W_tab, Kt_g);

  pcilt_main<<<512, NTHR, 0, stream>>>(x, bias, W_tab, Kt_g, out);
}

// Round 13
// 54.467 us; speedup vs baseline: 1.0393x; 1.0393x over previous
//
#include <hip/hip_runtime.h>

#define CIN   64
#define HW    128
#define COUT  128
#define TH    8
#define TW    32
#define PXR   34
#define NITER (TH + 2)      // 10 iterations (R11 two-barrier structure)
#define NTHR  512
#define HSTR  144           // bytes per histogram row (16B aligned)
#define SLOT  (PXR * HSTR)  // 4896 B per H ring slot
#define AKS   64            // u16 per AK o-row (128 B), XOR-swizzled blocks

// LDS layout (bytes):
//   [0, 19584)        Hm[4] ring slots, 34 rows x 144 B
//   [19584, 35968)    Kt i8[128][128] (prologue) / AK u16[128][64] (loop)
//   [35968, 36608)    Sx int[4][40] reduced (pc<<20)|ps per input row
//   [36608, 39872)    Sxp int[2][34][12] quad-partials
//   [39872, 40032)    Sx9 int[40]: 9-window sums for the current out-row
#define HM_OFF    0
#define KT_OFF    19584
#define SX_OFF    35968
#define SXP_OFF   36608
#define SX9_OFF   39872
#define LDS_BYTES 40064

typedef int v4i __attribute__((ext_vector_type(4)));

// lgkm-only barrier: drains LDS ops, leaves global loads/stores in flight.
__device__ __forceinline__ void wg_barrier() {
  asm volatile("s_waitcnt lgkmcnt(0)\n\ts_barrier" ::: "memory");
}

// sum over each aligned 4-lane quad via DPP (VALU pipe, no LDS traffic).
__device__ __forceinline__ int quad_sum(int v) {
  v += __builtin_amdgcn_mov_dpp(v, 0xB1, 0xF, 0xF, true);
  v += __builtin_amdgcn_mov_dpp(v, 0x4E, 0xF, 0xF, true);
  return v;
}

// ---------------------------------------------------------------------------
// Kernel 1: W_tab[o] = sum of quantized weights; Kt_g[o][v] i8 = K[v][o]-128
// where K[v][o] = #{w in o : qw*(128+v) > 32767}, v=0..127 (K<=255, ~7 sigma).
// ---------------------------------------------------------------------------
__global__ __launch_bounds__(512)
void build_tables(const float* __restrict__ weight, int* __restrict__ W_tab,
                  char* __restrict__ Kt_g) {
  __shared__ int qw_s[576];
  __shared__ int red_s[144];
  const int o = blockIdx.x;
  const int t = threadIdx.x;
  for (int j = t; j < 576; j += 512) {
    float w = weight[o * 576 + j];
    int q = (int)rintf(w * 255.f);
    qw_s[j] = q < 0 ? 0 : (q > 255 ? 255 : q);
  }
  __syncthreads();
  const int v = t >> 2, part = t & 3;
  const int i = 128 + v;                     // v==0 -> cnt=0 (qw*128<=32640)
  int cnt = 0;
  const int j0 = part * 144;
  for (int j = j0; j < j0 + 144; ++j) cnt += (qw_s[j] * i) > 32767 ? 1 : 0;
  cnt = quad_sum(cnt);
  if (part == 0) Kt_g[o * 128 + v] = (char)(cnt - 128);
  if (t < 144)
    red_s[t] = qw_s[t * 4] + qw_s[t * 4 + 1] + qw_s[t * 4 + 2] + qw_s[t * 4 + 3];
  __syncthreads();
  if (t == 0) {
    int s = 0;
    for (int kk = 0; kk < 144; ++kk) s += red_s[kk];
    W_tab[o] = s;
  }
}

// ---------------------------------------------------------------------------
// Kernel 2: prefetched quantize -> histogram (LDS atomics) -> i8 MFMA
// -> in-LDS AK[o][px] (b64 swizzled writes) -> vectorized emit.
// grid = 512 blocks 1D, XCD-remapped (b = bid&7). ~40 KB LDS, 2 blocks/CU.
// Wave roles in phase 2: 0-5 MFMA, 6 Sx-tree + Sx9, 7 zero next H slot.
//   iter r: stage row r | B1 | MFMA->AK, Sx9(out-row r-2), zero H r+1
//           | B2 | emit out-row r-2 (thread = one o x 8 px, 32B stores).
// ---------------------------------------------------------------------------
__global__ __launch_bounds__(NTHR, 4)
void pcilt_main(const float* __restrict__ x, const float* __restrict__ bias,
                const int* __restrict__ W_tab, const char* __restrict__ Kt_g,
                float* __restrict__ out) {
  __shared__ uint4 ldsv[LDS_BYTES / 16];
  char* ldsb = (char*)ldsv;
  unsigned char* HmB  = (unsigned char*)(ldsb + HM_OFF);
  unsigned char* KtB  = (unsigned char*)(ldsb + KT_OFF);
  unsigned short* AK  = (unsigned short*)(ldsb + KT_OFF);   // [128][64] u16
  int* Sx             = (int*)(ldsb + SX_OFF);              // [4][40]
  int* Sxp            = (int*)(ldsb + SXP_OFF);             // [2][34][12]
  int* Sx9            = (int*)(ldsb + SX9_OFF);             // [40]

  const int t   = (int)threadIdx.x;
  const int bid = (int)blockIdx.x;
  const int b  = bid & 7;                          // XCD owns one batch
  const int k  = bid >> 3;
  const int h0 = (k >> 2) * TH;
  const int w0 = (k & 3) * TW;

  for (int i = t; i < 4096; i += NTHR)
    ((unsigned int*)KtB)[i] = ((const unsigned int*)Kt_g)[i];
  {
    const uint4 z4 = make_uint4(0, 0, 0, 0);
    for (int i = t; i < 4 * SLOT / 16; i += NTHR) ((uint4*)HmB)[i] = z4;
  }

  const int l    = t & 15;
  const int slot = t >> 4;
  const int w    = t >> 6;
  const int kq   = (t >> 4) & 3;

  // emit mapping: one o per thread, 8 consecutive out pixels
  const int oe  = t & 127;
  const int pg  = t >> 7;                          // 0..3
  const float wfo = (float)W_tab[oe];
  const float bio = bias[oe];

  wg_barrier();

  // hoist B-fragments (Kt LDS is dead afterwards; AK reuses its space)
  v4i bfr[4][2];
  const int Mt = w >> 1, Nh = w & 1;
  if (w < 6) {
#pragma unroll
    for (int nt = 0; nt < 4; ++nt)
#pragma unroll
      for (int k64 = 0; k64 < 2; ++k64)
        bfr[nt][k64] = *(const v4i*)(KtB + (Nh * 64 + nt * 16 + l) * 128 +
                                     k64 * 64 + kq * 16);
  }

  float pf0[4], pf1[4];
  const float* xb = x + ((size_t)b * CIN + l * 4) * (HW * HW);
  const size_t cs = (size_t)HW * HW;

#define ISSUE(rn)                                                              \
  {                                                                            \
    const int iy  = h0 + (rn)-1;                                               \
    const int iyc = iy < 0 ? 0 : (iy > 127 ? 127 : iy);                        \
    const bool rok = (iy >= 0) && (iy < HW);                                   \
    int ix = w0 + slot - 1;                                                    \
    int ixc = ix < 0 ? 0 : (ix > 127 ? 127 : ix);                              \
    bool ok = rok && (ix >= 0) && (ix < HW);                                   \
    const float* xp = xb + (size_t)iyc * HW + ixc;                             \
    float v0 = xp[0], v1 = xp[cs], v2 = xp[2 * cs], v3 = xp[3 * cs];           \
    pf0[0] = ok ? v0 : 0.f; pf0[1] = ok ? v1 : 0.f;                            \
    pf0[2] = ok ? v2 : 0.f; pf0[3] = ok ? v3 : 0.f;                            \
    if (slot < 2) {                                                            \
      ix = w0 + 32 + slot - 1;                                                 \
      ixc = ix > 127 ? 127 : ix;                                               \
      ok = rok && (ix < HW);                                                   \
      const float* xq = xb + (size_t)iyc * HW + ixc;                           \
      float u0 = xq[0], u1 = xq[cs], u2 = xq[2 * cs], u3 = xq[3 * cs];         \
      pf1[0] = ok ? u0 : 0.f; pf1[1] = ok ? u1 : 0.f;                          \
      pf1[2] = ok ? u2 : 0.f; pf1[3] = ok ? u3 : 0.f;                          \
    }                                                                          \
  }

#define STAGEPX(pf, px)                                                        \
  {                                                                            \
    int q, iv0, iv1, iv2, iv3;                                                 \
    q = (int)rintf((pf)[0] * 255.f); iv0 = q < 0 ? 0 : (q > 255 ? 255 : q);    \
    q = (int)rintf((pf)[1] * 255.f); iv1 = q < 0 ? 0 : (q > 255 ? 255 : q);    \
    q = (int)rintf((pf)[2] * 255.f); iv2 = q < 0 ? 0 : (q > 255 ? 255 : q);    \
    q = (int)rintf((pf)[3] * 255.f); iv3 = q < 0 ? 0 : (q > 255 ? 255 : q);    \
    int pk = (((iv0 > 128) + (iv1 > 128) + (iv2 > 128) + (iv3 > 128)) << 20) + \
             (iv0 + iv1 + iv2 + iv3);                                          \
    pk = quad_sum(pk);                                                         \
    if ((l & 3) == 0) Sxp[sxpb + (px)*12 + (l >> 2)] = pk;                     \
    unsigned char* hp = Hc + (px)*HSTR;                                        \
    if (iv0 > 128) { int v = iv0 - 128; atomicAdd((unsigned int*)(hp + ((v >> 2) << 2)), 1u << ((v & 3) * 8)); } \
    if (iv1 > 128) { int v = iv1 - 128; atomicAdd((unsigned int*)(hp + ((v >> 2) << 2)), 1u << ((v & 3) * 8)); } \
    if (iv2 > 128) { int v = iv2 - 128; atomicAdd((unsigned int*)(hp + ((v >> 2) << 2)), 1u << ((v & 3) * 8)); } \
    if (iv3 > 128) { int v = iv3 - 128; atomicAdd((unsigned int*)(hp + ((v >> 2) << 2)), 1u << ((v & 3) * 8)); } \
  }

  ISSUE(0);

  for (int r = 0; r < NITER; ++r) {
    // ---------------- stage row r from prefetched regs; issue row r+1 ------
    {
      unsigned char* Hc = HmB + (r & 3) * SLOT;
      const int sxpb = (r & 1) * (34 * 12);
      STAGEPX(pf0, slot);
      if (slot < 2) STAGEPX(pf1, 32 + slot);
      if (r + 1 < NITER) ISSUE(r + 1);
    }
    wg_barrier();

    // ---------------- phase 2: MFMA (0-5) / Sx tree+Sx9 (6) / zero (7) -----
    if (r >= 2 && w < 6) {
      v4i acc[4];
#pragma unroll
      for (int nt = 0; nt < 4; ++nt) acc[nt] = (v4i){0, 0, 0, 0};
      const int prow = Mt * 16 + l;              // rows >=34 overflow into
#pragma unroll                                   // AK region: garbage D px,
      for (int st = 0; st < 3; ++st) {           // never consumed by emit
        const unsigned char* Hs = HmB + ((r - 2 + st) & 3) * SLOT +
                                  prow * HSTR + kq * 16;
#pragma unroll
        for (int k64 = 0; k64 < 2; ++k64) {
          const v4i a = *(const v4i*)(Hs + k64 * 64);
#pragma unroll
          for (int nt = 0; nt < 4; ++nt)
            acc[nt] = __builtin_amdgcn_mfma_i32_16x16x64_i8(a, bfr[nt][k64], acc[nt], 0, 0, 0);
        }
      }
      // AK[o][px] with XOR-swizzled 8-px blocks; 4x ds_write_b64 per thread.
      const int pbase = Mt * 16 + kq * 4;        // pixel base (4-aligned)
#pragma unroll
      for (int nt = 0; nt < 4; ++nt) {
        const int o = Nh * 64 + nt * 16 + l;
        const unsigned int lo = ((unsigned)acc[nt][0] & 0xFFFFu) | ((unsigned)acc[nt][1] << 16);
        const unsigned int hi = ((unsigned)acc[nt][2] & 0xFFFFu) | ((unsigned)acc[nt][3] << 16);
        const int sp = pbase ^ (((o >> 3) & 7) << 3);
        *(uint2*)(AK + o * AKS + sp) = make_uint2(lo, hi);
      }
    }
    if (w == 6) {                                // Sx tree, then Sx9 window
      const int L = t - 384;
      const int sb = (r & 1) * (34 * 12);
      if (L < 34) {
        const v4i sq = *(const v4i*)&Sxp[sb + L * 12];
        Sx[(r & 3) * 40 + L] = sq.x + sq.y + sq.z + sq.w;
      }
      if (r >= 2 && L < 32) {
        int v9 = 0;
#pragma unroll
        for (int q = 0; q < 3; ++q) {
          const int sl = (r - 2 + q) & 3;
          v9 += Sx[sl * 40 + L] + Sx[sl * 40 + L + 1] + Sx[sl * 40 + L + 2];
        }
        Sx9[L] = v9;
      }
    }
    if (w == 7) {                                // zero H slot r+1
      uint4* Hn = (uint4*)(HmB + ((r + 1) & 3) * SLOT);
      const uint4 z4 = make_uint4(0, 0, 0, 0);
      for (int i2 = t - 448; i2 < SLOT / 16; i2 += 64) Hn[i2] = z4;
    }
    wg_barrier();

    // ---------------- emit out-row h0 + r - 2: one o x 8 px per thread -----
    if (r >= 2) {
      const int h = h0 + r - 2;
      const int kx = (oe >> 3) & 7;
      const unsigned short* ar = AK + oe * AKS;
      const uint4 A0 = *(const uint4*)(ar + ((pg ^ kx) << 3));        // px 8pg..+7
      const uint4 A1 = *(const uint4*)(ar + (((pg + 1) ^ kx) << 3));  // px +8..+15
      const v4i S0 = *(const v4i*)(Sx9 + pg * 8);       // broadcast reads
      const v4i S1 = *(const v4i*)(Sx9 + pg * 8 + 4);
      const unsigned int dd[5] = {A0.x, A0.y, A0.z, A0.w, A1.x};
      int e[10];
#pragma unroll
      for (int i = 0; i < 10; ++i)
        e[i] = (int)(short)((dd[i >> 1] >> ((i & 1) * 16)) & 0xFFFFu);
      const int s[8] = {S0[0], S0[1], S0[2], S0[3], S1[0], S1[1], S1[2], S1[3]};
      float v[8];
#pragma unroll
      for (int j = 0; j < 8; ++j) {
        const int sx = s[j] & 0xFFFFF;
        const int sh = s[j] >> 20;
        const int k3 = e[j] + e[j + 1] + e[j + 2] + (sh << 7);
        v[j] = (float)sx * wfo - 65536.f * (float)k3 + bio;
      }
      float* op = out + (((size_t)b * COUT + oe) * HW + h) * HW + w0 + pg * 8;
      *(float4*)op       = make_float4(v[0], v[1], v[2], v[3]);
      *(float4*)(op + 4) = make_float4(v[4], v[5], v[6], v[7]);
    }
  }
}

// ---------------------------------------------------------------------------
extern "C" void kernel_launch(void* const* d_in, const int* in_sizes, int n_in,
                              void* d_out, int out_size, void* d_ws, size_t ws_size,
                              hipStream_t stream) {
  const float* x      = (const float*)d_in[0];
  const float* weight = (const float*)d_in[1];
  const float* bias   = (const float*)d_in[2];
  float* out = (float*)d_out;

  int*  W_tab = (int*)d_ws;
  char* Kt_g  = (char*)d_ws + 512;

  build_tables<<<128, 512, 0, stream>>>(weight, W_tab, Kt_g);

  pcilt_main<<<512, NTHR, 0, stream>>>(x, bias, W_tab, Kt_g, out);
}

// Round 14
// 44.452 us; speedup vs baseline: 1.2735x; 1.2253x over previous
//
#include <hip/hip_runtime.h>

#define CIN   64
#define HW    128
#define COUT  128
#define TH    8
#define TW    32
#define PXR   34
#define NITER 11
#define NTHR  512
#define HSTR  144            // bytes per histogram row (16B aligned)
#define AKSTR 136            // u16 per AK row -> 272 B
#define SLOT  (PXR * HSTR)   // 4896 B per H ring slot

// LDS layout (bytes):
//   [0, 29376)        Hm[6] ring slots, 34 rows x 144 B   (ring mod 6)
//   [29376, 55488)    AK u16[2][48][136] (26112 B); Kt i8[16384] overlaps
//                     this region during the prologue only
//   [55488, 56768)    Sx int[8][40] reduced (pc<<20)|ps per input row
//   [56768, 60032)    Sxp int[2][34][12] quad partials
#define HM_OFF    0
#define AK_OFF    29376
#define SX_OFF    55488
#define SXP_OFF   56768
#define LDS_BYTES 60032

typedef int v4i __attribute__((ext_vector_type(4)));

// lgkm-only barrier: drains LDS ops, leaves global loads/stores in flight.
__device__ __forceinline__ void wg_barrier() {
  asm volatile("s_waitcnt lgkmcnt(0)\n\ts_barrier" ::: "memory");
}

// sum over each aligned 4-lane quad via DPP (VALU pipe, no LDS traffic).
__device__ __forceinline__ int quad_sum(int v) {
  v += __builtin_amdgcn_mov_dpp(v, 0xB1, 0xF, 0xF, true);
  v += __builtin_amdgcn_mov_dpp(v, 0x4E, 0xF, 0xF, true);
  return v;
}

// ---------------------------------------------------------------------------
// Kernel 1: W_tab[o] = sum of quantized weights; Kt_g[o][v] i8 = K[v][o]-128
// where K[v][o] = #{w in o : qw*(128+v) > 32767}, v=0..127 (K<=255, ~7 sigma).
// ---------------------------------------------------------------------------
__global__ __launch_bounds__(512)
void build_tables(const float* __restrict__ weight, int* __restrict__ W_tab,
                  char* __restrict__ Kt_g) {
  __shared__ int qw_s[576];
  __shared__ int red_s[144];
  const int o = blockIdx.x;
  const int t = threadIdx.x;
  for (int j = t; j < 576; j += 512) {
    float w = weight[o * 576 + j];
    int q = (int)rintf(w * 255.f);
    qw_s[j] = q < 0 ? 0 : (q > 255 ? 255 : q);
  }
  __syncthreads();
  const int v = t >> 2, part = t & 3;
  const int i = 128 + v;                     // v==0 -> cnt=0 (qw*128<=32640)
  int cnt = 0;
  const int j0 = part * 144;
  for (int j = j0; j < j0 + 144; ++j) cnt += (qw_s[j] * i) > 32767 ? 1 : 0;
  cnt = quad_sum(cnt);
  if (part == 0) Kt_g[o * 128 + v] = (char)(cnt - 128);
  if (t < 144)
    red_s[t] = qw_s[t * 4] + qw_s[t * 4 + 1] + qw_s[t * 4 + 2] + qw_s[t * 4 + 3];
  __syncthreads();
  if (t == 0) {
    int s = 0;
    for (int kk = 0; kk < 144; ++kk) s += red_s[kk];
    W_tab[o] = s;
  }
}

// ---------------------------------------------------------------------------
// Kernel 2: single fat phase per iteration (pipe overlap), 1 barrier/iter.
// P(r): atomics(row r)->H[r%6] | MFMA(out r-3, H rows r-3..r-1)->AK[r&1]
//       | wave6: Sx tree(row r) | wave7: zero H[(r+2)%6]
//       | all: quantize(row r+1)->qv, Sxp[(r+1)&1] | ISSUE(r+2)
// barrier; emit(out r-3) from AK[r&1], Sx[(r-3..r-1)&7].
// grid = 512 blocks 1D, XCD-remapped (b = bid&7). 60 KB LDS, 2 blocks/CU.
// Stage double-pixels (px 32,33) on wave 7 (no MFMA) instead of wave 0.
// ---------------------------------------------------------------------------
__global__ __launch_bounds__(NTHR, 4)
void pcilt_main(const float* __restrict__ x, const float* __restrict__ bias,
                const int* __restrict__ W_tab, const char* __restrict__ Kt_g,
                float* __restrict__ out) {
  __shared__ uint4 ldsv[LDS_BYTES / 16];
  char* ldsb = (char*)ldsv;
  unsigned char* HmB  = (unsigned char*)(ldsb + HM_OFF);
  unsigned char* KtB  = (unsigned char*)(ldsb + AK_OFF);   // prologue only
  unsigned short* AKB = (unsigned short*)(ldsb + AK_OFF);  // [2][48][136]
  int* Sx             = (int*)(ldsb + SX_OFF);             // [8][40]
  int* Sxp            = (int*)(ldsb + SXP_OFF);            // [2][34][12]

  const int t   = (int)threadIdx.x;
  const int bid = (int)blockIdx.x;
  const int b  = bid & 7;                          // XCD owns one batch
  const int k  = bid >> 3;
  const int h0 = (k >> 2) * TH;
  const int w0 = (k & 3) * TW;

  for (int i = t; i < 4096; i += NTHR)
    ((unsigned int*)KtB)[i] = ((const unsigned int*)Kt_g)[i];
  {
    const uint4 z4 = make_uint4(0, 0, 0, 0);
    for (int i = t; i < 2 * SLOT / 16; i += NTHR) ((uint4*)HmB)[i] = z4;
  }

  const int l    = t & 15;
  const int slot = t >> 4;
  const int w    = t >> 6;
  const int kq   = (t >> 4) & 3;
  const int we   = t & 31;
  const int og   = t >> 5;

  float wf[8], bi[8];
#pragma unroll
  for (int m = 0; m < 8; ++m) {
    wf[m] = (float)W_tab[og * 8 + m];
    bi[m] = bias[og * 8 + m];
  }

  wg_barrier();                                    // Kt + H0/H1 visible

  // hoist B-fragments (Kt region dead afterwards; AK reuses it from P(3))
  v4i bfr[4][2];
  const int Mt = w >> 1, Nh = w & 1;
  if (w < 6) {
#pragma unroll
    for (int nt = 0; nt < 4; ++nt)
#pragma unroll
      for (int k64 = 0; k64 < 2; ++k64)
        bfr[nt][k64] = *(const v4i*)(KtB + (Nh * 64 + nt * 16 + l) * 128 +
                                     k64 * 64 + kq * 16);
  }

  float pf0[4], pf1[4];
  int qv[2][8];
  const float* xb = x + ((size_t)b * CIN + l * 4) * (HW * HW);
  const size_t cs = (size_t)HW * HW;

#define ISSUE(rn)                                                              \
  {                                                                            \
    const int iy  = h0 + (rn)-1;                                               \
    const int iyc = iy < 0 ? 0 : (iy > 127 ? 127 : iy);                        \
    const bool rok = (iy >= 0) && (iy < HW);                                   \
    int ix = w0 + slot - 1;                                                    \
    int ixc = ix < 0 ? 0 : (ix > 127 ? 127 : ix);                              \
    bool ok = rok && (ix >= 0) && (ix < HW);                                   \
    const float* xp = xb + (size_t)iyc * HW + ixc;                             \
    float v0 = xp[0], v1 = xp[cs], v2 = xp[2 * cs], v3 = xp[3 * cs];           \
    pf0[0] = ok ? v0 : 0.f; pf0[1] = ok ? v1 : 0.f;                            \
    pf0[2] = ok ? v2 : 0.f; pf0[3] = ok ? v3 : 0.f;                            \
    if (slot >= 30) {                                                          \
      ix = w0 + slot + 1;                          /* pixel slot+2 */          \
      ixc = ix > 127 ? 127 : ix;                                               \
      ok = rok && (ix < HW);                                                   \
      const float* xq = xb + (size_t)iyc * HW + ixc;                           \
      float u0 = xq[0], u1 = xq[cs], u2 = xq[2 * cs], u3 = xq[3 * cs];         \
      pf1[0] = ok ? u0 : 0.f; pf1[1] = ok ? u1 : 0.f;                          \
      pf1[2] = ok ? u2 : 0.f; pf1[3] = ok ? u3 : 0.f;                          \
    }                                                                          \
  }

// quantize 4 floats -> 4 ints in qn[base..], quad-reduce, write Sxp
#define QUANT4(pf, qn, base, px, sxpb)                                         \
  {                                                                            \
    int q;                                                                     \
    q = (int)rintf((pf)[0] * 255.f); (qn)[(base)+0] = q < 0 ? 0 : (q > 255 ? 255 : q); \
    q = (int)rintf((pf)[1] * 255.f); (qn)[(base)+1] = q < 0 ? 0 : (q > 255 ? 255 : q); \
    q = (int)rintf((pf)[2] * 255.f); (qn)[(base)+2] = q < 0 ? 0 : (q > 255 ? 255 : q); \
    q = (int)rintf((pf)[3] * 255.f); (qn)[(base)+3] = q < 0 ? 0 : (q > 255 ? 255 : q); \
    int pk = (((qn)[(base)+0] > 128) + ((qn)[(base)+1] > 128) +                \
              ((qn)[(base)+2] > 128) + ((qn)[(base)+3] > 128));                \
    pk = (pk << 20) + (qn)[(base)+0] + (qn)[(base)+1] + (qn)[(base)+2] + (qn)[(base)+3]; \
    pk = quad_sum(pk);                                                         \
    if ((l & 3) == 0) Sxp[(sxpb) + (px)*12 + (l >> 2)] = pk;                   \
  }

#define HIST4(q0, q1, q2, q3, px, Hc)                                          \
  {                                                                            \
    unsigned char* hp = (Hc) + (px)*HSTR;                                      \
    if ((q0) > 128) { int v = (q0) - 128; atomicAdd((unsigned int*)(hp + ((v >> 2) << 2)), 1u << ((v & 3) * 8)); } \
    if ((q1) > 128) { int v = (q1) - 128; atomicAdd((unsigned int*)(hp + ((v >> 2) << 2)), 1u << ((v & 3) * 8)); } \
    if ((q2) > 128) { int v = (q2) - 128; atomicAdd((unsigned int*)(hp + ((v >> 2) << 2)), 1u << ((v & 3) * 8)); } \
    if ((q3) > 128) { int v = (q3) - 128; atomicAdd((unsigned int*)(hp + ((v >> 2) << 2)), 1u << ((v & 3) * 8)); } \
  }

  // prologue: load row 0, quantize it (Sxp slot 0), issue row 1
  ISSUE(0);
  QUANT4(pf0, qv[0], 0, slot, 0);
  if (slot >= 30) QUANT4(pf1, qv[0], 4, slot + 2, 0);
  ISSUE(1);
  wg_barrier();                                    // Sxp[0] visible

#pragma unroll
  for (int r = 0; r < NITER; ++r) {
    // ---- (a) histogram atomics for row r (prepared last iteration) -------
    if (r <= 9) {
      unsigned char* Hc = HmB + (r % 6) * SLOT;
      const int* qc = qv[r & 1];
      HIST4(qc[0], qc[1], qc[2], qc[3], slot, Hc);
      if (slot >= 30) HIST4(qc[4], qc[5], qc[6], qc[7], slot + 2, Hc);
    }
    // ---- (b) MFMA: out-row r-3 from H rows r-3..r-1 -> AK[r&1] ------------
    if (r >= 3 && w < 6) {
      v4i acc[4];
#pragma unroll
      for (int nt = 0; nt < 4; ++nt) acc[nt] = (v4i){0, 0, 0, 0};
      const int prow = Mt * 16 + l;                // rows >=34: garbage reads
#pragma unroll                                     // (overflow into AK region)
      for (int st = 0; st < 3; ++st) {             // and garbage AK rows 34-47
        const unsigned char* Hs = HmB + ((r - 3 + st) % 6) * SLOT +
                                  prow * HSTR + kq * 16;
#pragma unroll
        for (int k64 = 0; k64 < 2; ++k64) {
          const v4i a = *(const v4i*)(Hs + k64 * 64);
#pragma unroll
          for (int nt = 0; nt < 4; ++nt)
            acc[nt] = __builtin_amdgcn_mfma_i32_16x16x64_i8(a, bfr[nt][k64], acc[nt], 0, 0, 0);
        }
      }
      unsigned short* AKw = AKB + (r & 1) * (48 * AKSTR);
      const int pbase = Mt * 16 + kq * 4;
#pragma unroll
      for (int nt = 0; nt < 4; ++nt) {
        const int o = Nh * 64 + nt * 16 + l;
#pragma unroll
        for (int rg = 0; rg < 4; ++rg)
          AKw[(pbase + rg) * AKSTR + o] = (unsigned short)acc[nt][rg];
      }
    }
    // ---- (c) wave 6: Sx tree for row r ------------------------------------
    if (w == 6 && r <= 9) {
      const int L = t - 384;
      if (L < 34) {
        const v4i sq = *(const v4i*)&Sxp[(r & 1) * (34 * 12) + L * 12];
        Sx[(r & 7) * 40 + L] = sq.x + sq.y + sq.z + sq.w;
      }
    }
    // ---- (d) wave 7: zero H slot (r+2)%6 ----------------------------------
    if (w == 7 && r <= 7) {
      uint4* Hn = (uint4*)(HmB + ((r + 2) % 6) * SLOT);
      const uint4 z4 = make_uint4(0, 0, 0, 0);
      for (int i2 = t - 448; i2 < SLOT / 16; i2 += 64) Hn[i2] = z4;
    }
    // ---- (e) quantize row r+1 (VALU, overlaps MFMA/LDS) -------------------
    if (r <= 8) {
      const int sxpb = ((r + 1) & 1) * (34 * 12);
      int* qn = qv[(r + 1) & 1];
      QUANT4(pf0, qn, 0, slot, sxpb);
      if (slot >= 30) QUANT4(pf1, qn, 4, slot + 2, sxpb);
    }
    // ---- (f) issue loads for row r+2 --------------------------------------
    if (r <= 7) ISSUE(r + 2);

    wg_barrier();

    // ---- emit out-row h0 + r - 3 from AK[r&1] -----------------------------
    if (r >= 3) {
      const int h = h0 + r - 3;
      const unsigned short* AKr = AKB + (r & 1) * (48 * AKSTR);
      int v9 = 0;
#pragma unroll
      for (int q = 0; q < 3; ++q) {
        const int sl = (r - 3 + q) & 7;
        v9 += Sx[sl * 40 + we] + Sx[sl * 40 + we + 1] + Sx[sl * 40 + we + 2];
      }
      const int sx9 = v9 & 0xFFFFF;
      const int sh9 = v9 >> 20;
      int k0 = 0, k1 = 0, k2 = 0, k3 = 0, k4 = 0, k5 = 0, k6 = 0, k7 = 0;
#pragma unroll
      for (int dx = 0; dx < 3; ++dx) {
        const uint4 p = *(const uint4*)&AKr[(we + dx) * AKSTR + og * 8];
        k0 += (int)(short)(p.x & 0xffffu); k1 += (int)(short)(p.x >> 16);
        k2 += (int)(short)(p.y & 0xffffu); k3 += (int)(short)(p.y >> 16);
        k4 += (int)(short)(p.z & 0xffffu); k5 += (int)(short)(p.z >> 16);
        k6 += (int)(short)(p.w & 0xffffu); k7 += (int)(short)(p.w >> 16);
      }
      const int kc = 128 * sh9;
      const float sxf = (float)sx9;
      float* op = out + (((size_t)b * COUT + og * 8) * HW + h) * HW + (w0 + we);
      const size_t os = (size_t)HW * HW;
      op[0 * os] = sxf * wf[0] - 65536.f * (float)(k0 + kc) + bi[0];
      op[1 * os] = sxf * wf[1] - 65536.f * (float)(k1 + kc) + bi[1];
      op[2 * os] = sxf * wf[2] - 65536.f * (float)(k2 + kc) + bi[2];
      op[3 * os] = sxf * wf[3] - 65536.f * (float)(k3 + kc) + bi[3];
      op[4 * os] = sxf * wf[4] - 65536.f * (float)(k4 + kc) + bi[4];
      op[5 * os] = sxf * wf[5] - 65536.f * (float)(k5 + kc) + bi[5];
      op[6 * os] = sxf * wf[6] - 65536.f * (float)(k6 + kc) + bi[6];
      op[7 * os] = sxf * wf[7] - 65536.f * (float)(k7 + kc) + bi[7];
    }
  }
}

// ---------------------------------------------------------------------------
extern "C" void kernel_launch(void* const* d_in, const int* in_sizes, int n_in,
                              void* d_out, int out_size, void* d_ws, size_t ws_size,
                              hipStream_t stream) {
  const float* x      = (const float*)d_in[0];
  const float* weight = (const float*)d_in[1];
  const float* bias   = (const float*)d_in[2];
  float* out = (float*)d_out;

  int*  W_tab = (int*)d_ws;
  char* Kt_g  = (char*)d_ws + 512;

  build_tables<<<128, 512, 0, stream>>>(weight, W_tab, Kt_g);

  pcilt_main<<<512, NTHR, 0, stream>>>(x, bias, W_tab, Kt_g, out);
}

// Round 15
// 44.338 us; speedup vs baseline: 1.2767x; 1.0026x over previous
//
#include <hip/hip_runtime.h>

#define CIN   64
#define HW    128
#define COUT  128
#define TH    8
#define TW    32
#define NITER 12
#define NTHR  512
#define HSTR  144            // bytes per histogram row (16B aligned)
#define SLOT  (34 * HSTR)    // 4896 B per H ring slot (34 padded px)
#define H3SL  (32 * HSTR)    // 4608 B per H3 ring slot (32 out px)

// LDS layout (bytes):
//   [0, 19584)        Hm[4] ring slots, 34 rows x 144 B
//   [19584, 38016)    H3[4] ring slots, 32 rows x 144 B (Kt i8[16384]
//                     overlays this region during the prologue only)
//   [38016, 39296)    Sx int[8][40] packed (pc<<20)|ps per input row
//   [39296, 42560)    Sxp int[2][34*12] quad partials
//   [42560, 42880)    Sx9 int[2][40] 9-window sums (double-buffered)
#define HM_OFF    0
#define H3_OFF    19584
#define SX_OFF    38016
#define SXP_OFF   39296
#define SX9_OFF   42560
#define LDS_BYTES 42880

typedef int v4i __attribute__((ext_vector_type(4)));

// lgkm-only barrier: drains LDS ops, leaves global loads/stores in flight.
__device__ __forceinline__ void wg_barrier() {
  asm volatile("s_waitcnt lgkmcnt(0)\n\ts_barrier" ::: "memory");
}

// sum over each aligned 4-lane quad via DPP (VALU pipe, no LDS traffic).
__device__ __forceinline__ int quad_sum(int v) {
  v += __builtin_amdgcn_mov_dpp(v, 0xB1, 0xF, 0xF, true);
  v += __builtin_amdgcn_mov_dpp(v, 0x4E, 0xF, 0xF, true);
  return v;
}

// ---------------------------------------------------------------------------
// Kernel 1: W_tab[o] = sum of quantized weights; Kt_g[o][v] i8 = K[v][o]-128
// where K[v][o] = #{w in o : qw*(128+v) > 32767}, v=0..127 (K<=255, ~7 sigma).
// ---------------------------------------------------------------------------
__global__ __launch_bounds__(512)
void build_tables(const float* __restrict__ weight, int* __restrict__ W_tab,
                  char* __restrict__ Kt_g) {
  __shared__ int qw_s[576];
  __shared__ int red_s[144];
  const int o = blockIdx.x;
  const int t = threadIdx.x;
  for (int j = t; j < 576; j += 512) {
    float w = weight[o * 576 + j];
    int q = (int)rintf(w * 255.f);
    qw_s[j] = q < 0 ? 0 : (q > 255 ? 255 : q);
  }
  __syncthreads();
  const int v = t >> 2, part = t & 3;
  const int i = 128 + v;                     // v==0 -> cnt=0 (qw*128<=32640)
  int cnt = 0;
  const int j0 = part * 144;
  for (int j = j0; j < j0 + 144; ++j) cnt += (qw_s[j] * i) > 32767 ? 1 : 0;
  cnt = quad_sum(cnt);
  if (part == 0) Kt_g[o * 128 + v] = (char)(cnt - 128);
  if (t < 144)
    red_s[t] = qw_s[t * 4] + qw_s[t * 4 + 1] + qw_s[t * 4 + 2] + qw_s[t * 4 + 3];
  __syncthreads();
  if (t == 0) {
    int s = 0;
    for (int kk = 0; kk < 144; ++kk) s += red_s[kk];
    W_tab[o] = s;
  }
}

// ---------------------------------------------------------------------------
// Kernel 2: quantize -> histogram (atomics) -> horizontal-3-sum histogram H3
// (u8, exact) -> i8 MFMA (K=384: 3 stacked H3 rows = vertical window) whose
// accumulator IS the final 9-window K-sum -> in-register emit (2 float4).
// No AK intermediate: the old 576-cyc i16 writes + 720-cyc emit reads die.
// grid = 512 blocks 1D, XCD-remapped (b=bid&7). ~42 KB LDS, 2 blocks/CU.
// Phase(r): atomics(H[r]) | H3[r-1] (thr<256) | MFMA+emit out r-4 (all 8
// waves: Mt=w>>2, Nh=w&3, nt 0..1) | Sx tree (wave7) | Sx9 out r-3 (wave6hi)
// | zero H[r+1] (waves4-5) | quantize r+1 | ISSUE r+2 | ONE barrier.
// ---------------------------------------------------------------------------
__global__ __launch_bounds__(NTHR, 4)
void pcilt_main(const float* __restrict__ x, const float* __restrict__ bias,
                const int* __restrict__ W_tab, const char* __restrict__ Kt_g,
                float* __restrict__ out) {
  __shared__ uint4 ldsv[LDS_BYTES / 16];
  char* ldsb = (char*)ldsv;
  unsigned char* HmB = (unsigned char*)(ldsb + HM_OFF);
  unsigned char* H3B = (unsigned char*)(ldsb + H3_OFF);
  unsigned char* KtB = (unsigned char*)(ldsb + H3_OFF);   // prologue overlay
  int* Sx  = (int*)(ldsb + SX_OFF);                       // [8][40]
  int* Sxp = (int*)(ldsb + SXP_OFF);                      // [2][34*12]
  int* Sx9 = (int*)(ldsb + SX9_OFF);                      // [2][40]

  const int t   = (int)threadIdx.x;
  const int bid = (int)blockIdx.x;
  const int b  = bid & 7;                                 // XCD owns one batch
  const int k  = bid >> 3;
  const int h0 = (k >> 2) * TH;
  const int w0 = (k & 3) * TW;

  for (int i = t; i < 4096; i += NTHR)
    ((unsigned int*)KtB)[i] = ((const unsigned int*)Kt_g)[i];
  {
    const uint4 z4 = make_uint4(0, 0, 0, 0);
    for (int i = t; i < SLOT / 16; i += NTHR) ((uint4*)HmB)[i] = z4;  // H[0]
  }

  const int l    = t & 15;
  const int slot = t >> 4;
  const int wv   = t >> 6;
  const int kq   = (t >> 4) & 3;
  const int Mt   = wv >> 2;                // 0..1: px tile
  const int Nh   = wv & 3;                 // 0..3: o quarter
  const int o0   = Nh * 32 + l;            // thread's o (nt adds +16)

  const float wfo0 = (float)W_tab[o0],      bio0 = bias[o0];
  const float wfo1 = (float)W_tab[o0 + 16], bio1 = bias[o0 + 16];

  float pf0[4], pf1[4];
  int qv[2][8];
  const float* xb = x + ((size_t)b * CIN + l * 4) * (HW * HW);
  const size_t cs = (size_t)HW * HW;

#define ISSUE(rn)                                                              \
  {                                                                            \
    const int iy  = h0 + (rn)-1;                                               \
    const int iyc = iy < 0 ? 0 : (iy > 127 ? 127 : iy);                        \
    const bool rok = (iy >= 0) && (iy < HW);                                   \
    int ix = w0 + slot - 1;                                                    \
    int ixc = ix < 0 ? 0 : (ix > 127 ? 127 : ix);                              \
    bool ok = rok && (ix >= 0) && (ix < HW);                                   \
    const float* xp = xb + (size_t)iyc * HW + ixc;                             \
    float v0 = xp[0], v1 = xp[cs], v2 = xp[2 * cs], v3 = xp[3 * cs];           \
    pf0[0] = ok ? v0 : 0.f; pf0[1] = ok ? v1 : 0.f;                            \
    pf0[2] = ok ? v2 : 0.f; pf0[3] = ok ? v3 : 0.f;                            \
    if (slot >= 30) {                                                          \
      ix = w0 + slot + 1;                          /* pixel slot+2 */          \
      ixc = ix > 127 ? 127 : ix;                                               \
      ok = rok && (ix < HW);                                                   \
      const float* xq = xb + (size_t)iyc * HW + ixc;                           \
      float u0 = xq[0], u1 = xq[cs], u2 = xq[2 * cs], u3 = xq[3 * cs];         \
      pf1[0] = ok ? u0 : 0.f; pf1[1] = ok ? u1 : 0.f;                          \
      pf1[2] = ok ? u2 : 0.f; pf1[3] = ok ? u3 : 0.f;                          \
    }                                                                          \
  }

#define QUANT4(pf, qn, base, px, sxpb)                                         \
  {                                                                            \
    int q;                                                                     \
    q = (int)rintf((pf)[0] * 255.f); (qn)[(base)+0] = q < 0 ? 0 : (q > 255 ? 255 : q); \
    q = (int)rintf((pf)[1] * 255.f); (qn)[(base)+1] = q < 0 ? 0 : (q > 255 ? 255 : q); \
    q = (int)rintf((pf)[2] * 255.f); (qn)[(base)+2] = q < 0 ? 0 : (q > 255 ? 255 : q); \
    q = (int)rintf((pf)[3] * 255.f); (qn)[(base)+3] = q < 0 ? 0 : (q > 255 ? 255 : q); \
    int pk = (((qn)[(base)+0] > 128) + ((qn)[(base)+1] > 128) +                \
              ((qn)[(base)+2] > 128) + ((qn)[(base)+3] > 128));                \
    pk = (pk << 20) + (qn)[(base)+0] + (qn)[(base)+1] + (qn)[(base)+2] + (qn)[(base)+3]; \
    pk = quad_sum(pk);                                                         \
    if ((l & 3) == 0) Sxp[(sxpb) + (px)*12 + (l >> 2)] = pk;                   \
  }

#define HIST4(q0, q1, q2, q3, px, Hc)                                          \
  {                                                                            \
    unsigned char* hp = (Hc) + (px)*HSTR;                                      \
    if ((q0) > 128) { int v = (q0) - 128; atomicAdd((unsigned int*)(hp + ((v >> 2) << 2)), 1u << ((v & 3) * 8)); } \
    if ((q1) > 128) { int v = (q1) - 128; atomicAdd((unsigned int*)(hp + ((v >> 2) << 2)), 1u << ((v & 3) * 8)); } \
    if ((q2) > 128) { int v = (q2) - 128; atomicAdd((unsigned int*)(hp + ((v >> 2) << 2)), 1u << ((v & 3) * 8)); } \
    if ((q3) > 128) { int v = (q3) - 128; atomicAdd((unsigned int*)(hp + ((v >> 2) << 2)), 1u << ((v & 3) * 8)); } \
  }

  ISSUE(0);
  wg_barrier();                                  // Kt + H[0] zero visible

  // hoist B-fragments from Kt (H3 region is free to overwrite from r=1 on)
  v4i bfr[2][2];
#pragma unroll
  for (int nt = 0; nt < 2; ++nt)
#pragma unroll
    for (int k64 = 0; k64 < 2; ++k64)
      bfr[nt][k64] = *(const v4i*)(KtB + (o0 + nt * 16) * 128 + k64 * 64 + kq * 16);

  QUANT4(pf0, qv[0], 0, slot, 0);
  if (slot >= 30) QUANT4(pf1, qv[0], 4, slot + 2, 0);
  ISSUE(1);
  wg_barrier();                                  // Sxp[0] visible, bfr done

#pragma unroll
  for (int r = 0; r < NITER; ++r) {
    // ---- (a) histogram atomics for row r ----------------------------------
    if (r <= 9) {
      unsigned char* Hc = HmB + (r & 3) * SLOT;
      const int* qc = qv[r & 1];
      HIST4(qc[0], qc[1], qc[2], qc[3], slot, Hc);
      if (slot >= 30) HIST4(qc[4], qc[5], qc[6], qc[7], slot + 2, Hc);
    }
    // ---- (b) H3[r-1]: horizontal 3-sum, u8-exact dword adds ---------------
    if (r >= 1 && r <= 10 && t < 256) {
      const int px = t & 31, ch = (t >> 5) * 16;
      const unsigned char* hs = HmB + ((r - 1) & 3) * SLOT + px * HSTR + ch;
      const uint4 a0 = *(const uint4*)hs;
      const uint4 a1 = *(const uint4*)(hs + HSTR);
      const uint4 a2 = *(const uint4*)(hs + 2 * HSTR);
      uint4 s;
      s.x = a0.x + a1.x + a2.x; s.y = a0.y + a1.y + a2.y;
      s.z = a0.z + a1.z + a2.z; s.w = a0.w + a1.w + a2.w;
      *(uint4*)(H3B + ((r - 1) & 3) * H3SL + px * HSTR + ch) = s;
    }
    // ---- (c) MFMA out-row j=r-4 + in-register emit ------------------------
    if (r >= 4) {
      v4i acc0 = (v4i){0, 0, 0, 0}, acc1 = (v4i){0, 0, 0, 0};
#pragma unroll
      for (int st = 0; st < 3; ++st) {
        const unsigned char* Hs = H3B + ((r - 4 + st) & 3) * H3SL +
                                  (Mt * 16 + l) * HSTR + kq * 16;
#pragma unroll
        for (int k64 = 0; k64 < 2; ++k64) {
          const v4i a = *(const v4i*)(Hs + k64 * 64);
          acc0 = __builtin_amdgcn_mfma_i32_16x16x64_i8(a, bfr[0][k64], acc0, 0, 0, 0);
          acc1 = __builtin_amdgcn_mfma_i32_16x16x64_i8(a, bfr[1][k64], acc1, 0, 0, 0);
        }
      }
      const int j = r - 4, h = h0 + j, px0 = Mt * 16 + kq * 4;
      const v4i s9 = *(const v4i*)&Sx9[(j & 1) * 40 + px0];
      float4 u0, u1;
#pragma unroll
      for (int rg = 0; rg < 4; ++rg) {
        const int sx = s9[rg] & 0xFFFFF;
        const int sh = s9[rg] >> 20;
        ((float*)&u0)[rg] = (float)sx * wfo0 - 65536.f * (float)(acc0[rg] + (sh << 7)) + bio0;
        ((float*)&u1)[rg] = (float)sx * wfo1 - 65536.f * (float)(acc1[rg] + (sh << 7)) + bio1;
      }
      float* op = out + (((size_t)b * COUT + o0) * HW + h) * HW + w0 + px0;
      *(float4*)op = u0;
      *(float4*)(op + 16 * (size_t)(HW * HW)) = u1;
    }
    // ---- (d) wave 7: Sx tree for row r ------------------------------------
    if (r <= 9 && wv == 7) {
      const int L = t - 448;
      if (L < 34) {
        const v4i sq = *(const v4i*)&Sxp[(r & 1) * 408 + L * 12];
        Sx[(r & 7) * 40 + L] = sq.x + sq.y + sq.z + sq.w;
      }
    }
    // ---- (e) wave 6 upper: Sx9 9-window for out-row r-3 -------------------
    if (r >= 3 && r <= 10 && wv == 6 && (t & 32)) {
      const int L = t - 416;                       // 0..31
      int v9 = 0;
#pragma unroll
      for (int q = 0; q < 3; ++q) {
        const int sl = ((r - 3 + q) & 7) * 40;
        v9 += Sx[sl + L] + Sx[sl + L + 1] + Sx[sl + L + 2];
      }
      Sx9[((r - 3) & 1) * 40 + L] = v9;
    }
    // ---- (f) waves 4-5: zero H slot r+1 -----------------------------------
    if (r <= 8 && wv >= 4 && wv < 6) {
      uint4* Hn = (uint4*)(HmB + ((r + 1) & 3) * SLOT);
      const uint4 z4 = make_uint4(0, 0, 0, 0);
      for (int i2 = t - 256; i2 < SLOT / 16; i2 += 128) Hn[i2] = z4;
    }
    // ---- (g) quantize row r+1 (VALU) --------------------------------------
    if (r <= 8) {
      const int sxpb = ((r + 1) & 1) * 408;
      int* qn = qv[(r + 1) & 1];
      QUANT4(pf0, qn, 0, slot, sxpb);
      if (slot >= 30) QUANT4(pf1, qn, 4, slot + 2, sxpb);
    }
    // ---- (h) issue loads for row r+2 --------------------------------------
    if (r <= 7) ISSUE(r + 2);

    wg_barrier();
  }
}

// ---------------------------------------------------------------------------
extern "C" void kernel_launch(void* const* d_in, const int* in_sizes, int n_in,
                              void* d_out, int out_size, void* d_ws, size_t ws_size,
                              hipStream_t stream) {
  const float* x      = (const float*)d_in[0];
  const float* weight = (const float*)d_in[1];
  const float* bias   = (const float*)d_in[2];
  float* out = (float*)d_out;

  int*  W_tab = (int*)d_ws;
  char* Kt_g  = (char*)d_ws + 512;

  build_tables<<<128, 512, 0, stream>>>(weight, W_tab, Kt_g);

  pcilt_main<<<512, NTHR, 0, stream>>>(x, bias, W_tab, Kt_g, out);
}